// Round 15
// baseline (93.498 us; speedup 1.0000x reference)
//
#include <hip/hip_runtime.h>
#include <hip/hip_bf16.h>

// Problem constants
#define FIN 250
#define NROWS 129024               // 2048*63
#define NT 8                       // tiles per block
#define NBLK 1008                  // 1008*8 = 8064 16-row tiles, exact

typedef short short8 __attribute__((ext_vector_type(8)));
typedef float f32x4 __attribute__((ext_vector_type(4)));

__device__ __forceinline__ short f2bf(float f) {
    __bf16 b = (__bf16)f;
    return __builtin_bit_cast(short, b);
}

#define WAITV(n) asm volatile("s_waitcnt vmcnt(" #n ")" ::: "memory")
#define WAITL    asm volatile("s_waitcnt lgkmcnt(0)" ::: "memory")
#define SCHEDF   __builtin_amdgcn_sched_barrier(0)
#define HWBAR do { asm volatile("" ::: "memory"); __builtin_amdgcn_s_barrier(); \
                   asm volatile("" ::: "memory"); } while (0)

// LDS map (32 KiB/block)
#define AFR0 0                     // bf16 afrag buffer, tile parity 0 (8 KiB)
#define AFR1 8192                  // bf16 afrag buffer, tile parity 1 (8 KiB)
#define OB   16384                 // fp32 out-staging tile, 16 rows x 1024B (16 KiB)

// Issue 4 coalesced 1KB register loads for one tile (wave wv owns rows wv*4..+3).
// Per-lane addr = rowbase + lane*16; overruns past byte 1000 land in the next row
// (in-bounds, feeds k>=250 pad slots which multiply zeroed W columns); the very
// last row is redirected to the 1024B zero-padded xlast copy.
__device__ __forceinline__ void load_tile(uint4 (&lb)[4], const float* __restrict__ x,
                                          const float* __restrict__ xlast,
                                          int tile, int wv, int lane) {
    #pragma unroll
    for (int rr = 0; rr < 4; ++rr) {
        int grow = tile * 16 + wv * 4 + rr;
        const char* g = (grow == NROWS - 1) ? (const char*)xlast
                                            : (const char*)x + (size_t)grow * 1000u;
        lb[rr] = *(const uint4*)(g + lane * 16);
    }
}

// Pre-kernel: W^T bf16 image, LINEAR [c(256)][k(256 padded, k-pairs packed)],
// zero-padded rows/cols; plus zero-padded copy of the last x row.
__global__ void __launch_bounds__(256)
wt_prep(const float* __restrict__ W, const float* __restrict__ x,
        unsigned* __restrict__ Wt, float* __restrict__ xlast) {
    int i = blockIdx.x * 256 + threadIdx.x;     // 128 blocks x 256 = 32768 words
    unsigned c  = (unsigned)i >> 7;             // 0..255
    unsigned kp = (unsigned)i & 127u;           // 0..127
    unsigned k0 = 2u * kp;
    unsigned lo = 0u, hi = 0u;
    if (c < FIN) {
        if (k0 < FIN)      lo = (unsigned)(unsigned short)f2bf(W[k0 * FIN + c]);
        if (k0 + 1u < FIN) hi = (unsigned)(unsigned short)f2bf(W[(k0 + 1u) * FIN + c]);
    }
    Wt[(c << 7) + kp] = lo | (hi << 16);
    if (blockIdx.x == 0) {
        int t = threadIdx.x;                    // 256 floats = 1024 B
        xlast[t] = (t < FIN) ? x[(size_t)(NROWS - 1) * FIN + t] : 0.f;
    }
}

// 256-thr blocks, reg-staged x, fused convert+repack, counted-vmcnt ping-pong.
// CHIP-SYNCHRONIZED tile interleave: tile = bid + i*NBLK, so at any instant all
// 1008 blocks read/write inside one contiguous ~16MB window (DRAM row locality).
__global__ void __launch_bounds__(256, 1)
gat_gemm(const float* __restrict__ x, const unsigned short* __restrict__ Wt,
         const float* __restrict__ xlast, const float* __restrict__ bias,
         float* __restrict__ out)
{
    __shared__ __align__(16) char lds[32768];

    const int tid  = threadIdx.x;
    const int lane = tid & 63;
    const int wv   = tid >> 6;        // 0..3: owns cols wv*64 .. wv*64+63, rows wv*4..+3
    const int m    = lane & 15;
    const int kg   = lane >> 4;

    // ---- B-fragments in registers for the whole kernel (loaded once, L2/L3-hot) ----
    short8 b[4][8];
    #pragma unroll
    for (int f = 0; f < 4; ++f)
        #pragma unroll
        for (int kk = 0; kk < 8; ++kk)
            b[f][kk] = *(const short8*)((const char*)Wt
                         + ((size_t)(wv * 64 + f * 16 + m) << 9) + kk * 64 + kg * 16);

    float bc[4];
    #pragma unroll
    for (int f = 0; f < 4; ++f) {
        int c = wv * 64 + f * 16 + m;
        bc[f] = (c < FIN) ? bias[c] : 0.f;
    }

    char* const ob = lds + OB;
    // repack writer decomposition: lane holds floats k=4*lane..4*lane+3 of each row
    const int wkk   = lane >> 3;          // frag kk
    const int wkg   = (lane >> 1) & 3;    // frag kg
    const int whalf = lane & 1;           // frag half (j 0-3 vs 4-7)
    const unsigned wroff = (unsigned)(wkk * 1024 + wkg * 256 + whalf * 8);

    WAITV(0); SCHEDF;                     // b/bias loads drained: clean vmcnt ledger

    const int bid = blockIdx.x;
    uint4 lbA[4], lbB[4];                 // register ping-pong tile buffers
    load_tile(lbA, x, xlast, bid,        wv, lane);
    load_tile(lbB, x, xlast, bid + NBLK, wv, lane);
    SCHEDF;

    #pragma unroll 1
    for (int i = 0; i < NT; ++i) {
        const int t = bid + i * NBLK;     // interleaved ownership (16MB moving window)
        // Counted drain of loads(t). Ledger (4 loads + 8 stores per iter, loads
        // issued mid-iter i-2): newer = stores(i-2)8 + loads(t+1)4 + stores(i-1)8.
        switch (i) {
            case 0:      WAITV(4);  break;   // loads(t1) only
            case 1:      WAITV(12); break;   // loads(t2)4 + stores(0)8
            case NT - 1: WAITV(16); break;   // loads(tNT) never issued
            default:     WAITV(20); break;
        }
        SCHEDF;

        // ---- convert + repack from registers -> fragment-layout LDS ----
        {
            char* const afrD = lds + ((i & 1) ? AFR1 : AFR0);
            const uint4* lb = (i & 1) ? lbB : lbA;
            #pragma unroll
            for (int rr = 0; rr < 4; ++rr) {
                int row = wv * 4 + rr;
                float v0 = __builtin_bit_cast(float, lb[rr].x);
                float v1 = __builtin_bit_cast(float, lb[rr].y);
                float v2 = __builtin_bit_cast(float, lb[rr].z);
                float v3 = __builtin_bit_cast(float, lb[rr].w);
                unsigned lo = (unsigned)(unsigned short)f2bf(v0)
                            | ((unsigned)(unsigned short)f2bf(v1) << 16);
                unsigned hi = (unsigned)(unsigned short)f2bf(v2)
                            | ((unsigned)(unsigned short)f2bf(v3) << 16);
                *(uint2*)(afrD + wroff + (unsigned)(((row ^ wkk) * 16)))
                    = make_uint2(lo, hi);
            }
        }
        SCHEDF;
        // ---- reissue freed buffer with tile t+2 (in flight across compute) ----
        if (i + 2 < NT) {
            if (i & 1) load_tile(lbB, x, xlast, t + 2 * NBLK, wv, lane);
            else       load_tile(lbA, x, xlast, t + 2 * NBLK, wv, lane);
        }
        SCHEDF;
        WAITL;
        HWBAR;                          // afrag(t) ready for all waves

        // ---- compute: 8 kk x 4 col-frags; conflict-free b128 A-reads ----
        const char* afrD = lds + ((i & 1) ? AFR1 : AFR0);
        f32x4 acc[4];
        #pragma unroll
        for (int f = 0; f < 4; ++f) acc[f] = (f32x4){bc[f], bc[f], bc[f], bc[f]};
        #pragma unroll
        for (int kk = 0; kk < 8; ++kk) {
            short8 af = *(const short8*)(afrD + kk * 1024 + kg * 256 + ((m ^ kk) * 16));
            #pragma unroll
            for (int f = 0; f < 4; ++f)
                acc[f] = __builtin_amdgcn_mfma_f32_16x16x32_bf16(af, b[f][kk], acc[f], 0, 0, 0);
        }

        // ---- out-stage: acc -> LDS tile (row-major, pitch 1024) ----
        // C/D layout: col = lane&15 (=m), row = kg*4 + j
        #pragma unroll
        for (int f = 0; f < 4; ++f)
            #pragma unroll
            for (int j = 0; j < 4; ++j)
                *(float*)(ob + (kg * 4 + j) * 1024 + (unsigned)(wv * 64 + f * 16 + m) * 4)
                    = acc[f][j];
        WAITL;
        HWBAR;                          // all waves' fragments staged

        // ---- contiguous stores: 4 rows per wave, 1KB-linear bursts (8 vmem) ----
        #pragma unroll
        for (int rr = 0; rr < 4; ++rr) {
            int row = wv * 4 + rr;
            float4 v = *(const float4*)(ob + row * 1024 + lane * 16);
            char* op = (char*)out + ((size_t)t * 16 + row) * 1000u;
            if (lane < 62)  *(float4*)(op + lane * 16) = v;                 // 0..992
            if (lane == 62) *(float2*)(op + 992) = make_float2(v.x, v.y);   // 992..1000
        }
    }
}

// 63-node GAT attention over rows 0..62 of out (holding h+bias). Exact: uniform
// logit shifts cancel in softmax and sum(alpha)=1 folds the bias through the mix.
__global__ void __launch_bounds__(1024, 1)
gat_attn(const float* __restrict__ att_src, const float* __restrict__ att_dst,
         float* __restrict__ out)
{
    __shared__ float hs[63 * 252];
    __shared__ float asrc[64], adst[64];
    __shared__ float alpha[63 * 64];

    const int tid = threadIdx.x;

    for (int idx = tid; idx < 63 * FIN; idx += 1024) {
        int r = idx / FIN, f = idx - r * FIN;
        hs[r * 252 + f] = out[idx];
    }
    __syncthreads();

    {   // logits: 16 threads per row, shfl-reduce
        int r = tid >> 4, t = tid & 15;
        float s1 = 0.f, s2 = 0.f;
        if (r < 63) {
            for (int k = t; k < FIN; k += 16) {
                float h = hs[r * 252 + k];
                s1 += h * att_src[k];
                s2 += h * att_dst[k];
            }
        }
        #pragma unroll
        for (int o = 8; o >= 1; o >>= 1) {
            s1 += __shfl_xor(s1, o, 16);
            s2 += __shfl_xor(s2, o, 16);
        }
        if (r < 63 && t == 0) { asrc[r] = s1; adst[r] = s2; }
    }
    __syncthreads();

    {   // softmax per dst row: 16 threads per row
        int d = tid >> 4, t = tid & 15;
        if (d < 63) {
            float ad = adst[d];
            float e_[4];
            float mx = -1e30f;
            #pragma unroll
            for (int q = 0; q < 4; ++q) {
                int sdx = t + q * 16;
                float e = -1e30f;
                if (sdx < 63) {
                    e = asrc[sdx] + ad;
                    e = e > 0.f ? e : 0.2f * e;     // leaky_relu slope 0.2
                }
                e_[q] = e;
                mx = fmaxf(mx, e);
            }
            #pragma unroll
            for (int o = 8; o >= 1; o >>= 1) mx = fmaxf(mx, __shfl_xor(mx, o, 16));
            float den = 0.f;
            #pragma unroll
            for (int q = 0; q < 4; ++q) {
                int sdx = t + q * 16;
                float ex = (sdx < 63) ? __expf(e_[q] - mx) : 0.f;
                e_[q] = ex;
                den += ex;
            }
            #pragma unroll
            for (int o = 8; o >= 1; o >>= 1) den += __shfl_xor(den, o, 16);
            float rd = 1.f / den;
            #pragma unroll
            for (int q = 0; q < 4; ++q) {
                int sdx = t + q * 16;
                if (sdx < 63) alpha[d * 64 + sdx] = e_[q] * rd;
            }
        }
    }
    __syncthreads();

    for (int idx = tid; idx < 63 * FIN; idx += 1024) {
        int d = idx / FIN, f = idx - d * FIN;
        float v = 0.f;
        for (int sdx = 0; sdx < 63; ++sdx)
            v += alpha[d * 64 + sdx] * hs[sdx * 252 + f];
        out[idx] = v;
    }
}

extern "C" void kernel_launch(void* const* d_in, const int* in_sizes, int n_in,
                              void* d_out, int out_size, void* d_ws, size_t ws_size,
                              hipStream_t stream) {
    (void)in_sizes; (void)n_in; (void)ws_size; (void)out_size;
    const float* x        = (const float*)d_in[0];
    const float* W        = (const float*)d_in[1];
    const float* att_src  = (const float*)d_in[2];
    const float* att_dst  = (const float*)d_in[3];
    const float* bias     = (const float*)d_in[4];
    float* out            = (float*)d_out;
    unsigned* Wt          = (unsigned*)d_ws;                       // 128 KiB image
    float* xlast          = (float*)((char*)d_ws + 131072);        // 1 KiB padded row

    wt_prep<<<128, 256, 0, stream>>>(W, x, Wt, xlast);
    gat_gemm<<<NBLK, 256, 0, stream>>>(x, (const unsigned short*)Wt, xlast, bias, out);
    gat_attn<<<1, 1024, 0, stream>>>(att_src, att_dst, out);
}